// Round 1
// baseline (45.496 us; speedup 1.0000x reference)
//
#include <hip/hip_runtime.h>

#define S_LEN 512
#define H_DIM 768
#define BS_TOK 8192      // B*S
#define NCOLS 80         // 64 mlp + 2 proj + 14 zero-pad
#define KCH 64           // K chunk staged in LDS
#define BM 64            // rows per block (4 waves x 16)

typedef __attribute__((ext_vector_type(8))) short short8v;
typedef __attribute__((ext_vector_type(4))) short short4v;
typedef __attribute__((ext_vector_type(4))) float f32x4;

__device__ __forceinline__ short f2bf(float f) {
  union { float f; unsigned u; } x; x.f = f;
  unsigned r = x.u + 0x7fffu + ((x.u >> 16) & 1u);  // round-to-nearest-even
  return (short)(r >> 16);
}

// ---- prep: Wcat[80][768] bf16, K-contiguous rows.
// row c<64: term_weight[k]*w1[k][c]; row 64/65: w_score[:,0/1]; rows 66..79: 0.
__global__ __launch_bounds__(256) void kprep(const float* __restrict__ tw,
                                             const float* __restrict__ w1,
                                             const float* __restrict__ wsc,
                                             short* __restrict__ wcat) {
  int i = blockIdx.x * 256 + threadIdx.x;
  if (i >= NCOLS * H_DIM) return;
  int c = i / H_DIM, k = i - c * H_DIM;
  float v = 0.f;
  if (c < 64)       v = tw[k] * w1[k * 64 + c];
  else if (c == 64) v = wsc[k * 2 + 0];
  else if (c == 65) v = wsc[k * 2 + 1];
  wcat[i] = f2bf(v);
}

// ---- k1: C = hidden @ Wcat^T-layout, fused relu-MLP epilogue -> logit, p
__global__ __launch_bounds__(256) void k1(const float* __restrict__ hidden,
                                          const short* __restrict__ wcat,
                                          const float* __restrict__ b1,
                                          const float* __restrict__ w2,
                                          const float* __restrict__ b2,
                                          float* __restrict__ logit,
                                          float* __restrict__ pbuf) {
  __shared__ short as[BM * 72];      // 64 rows x 72 (cols 0..63 used), stride 144B: 2-way banks
  __shared__ short bs[NCOLS * 72];   // 80 rows x 72
  const int tid  = threadIdx.x;
  const int t0   = blockIdx.x * BM;
  const int w    = tid >> 6;
  const int lane = tid & 63;
  const int ci   = lane & 15;
  const int kg   = (lane >> 4) * 8;
  const int arow = w * 16 + ci;

  f32x4 acc[5];
#pragma unroll
  for (int nt = 0; nt < 5; ++nt) acc[nt] = (f32x4){0.f, 0.f, 0.f, 0.f};

  for (int cc = 0; cc < H_DIM / KCH; ++cc) {
    const int k0 = cc * KCH;
    __syncthreads();
    // stage A tile: 64 rows x 64 cols fp32 -> bf16 (coalesced float4 loads)
#pragma unroll
    for (int i = 0; i < 4; ++i) {
      int f = tid + 256 * i;          // 0..1023
      int r = f >> 4, c4 = f & 15;
      const float4 v = *reinterpret_cast<const float4*>(
          hidden + (size_t)(t0 + r) * H_DIM + k0 + c4 * 4);
      short4v bv;
      bv[0] = f2bf(v.x); bv[1] = f2bf(v.y); bv[2] = f2bf(v.z); bv[3] = f2bf(v.w);
      *reinterpret_cast<short4v*>(&as[r * 72 + c4 * 4]) = bv;
    }
    // stage B chunk: 80 x 64 bf16 copy (short8)
    for (int i = tid; i < NCOLS * (KCH / 8); i += 256) {  // 640
      int r = i >> 3, c8 = i & 7;
      short8v v = *reinterpret_cast<const short8v*>(wcat + r * H_DIM + k0 + c8 * 8);
      *reinterpret_cast<short8v*>(&bs[r * 72 + c8 * 8]) = v;
    }
    __syncthreads();
#pragma unroll
    for (int ks = 0; ks < KCH; ks += 32) {
      short8v a = *reinterpret_cast<const short8v*>(&as[arow * 72 + ks + kg]);
#pragma unroll
      for (int nt = 0; nt < 5; ++nt) {
        short8v bb = *reinterpret_cast<const short8v*>(&bs[(nt * 16 + ci) * 72 + ks + kg]);
        acc[nt] = __builtin_amdgcn_mfma_f32_16x16x32_bf16(a, bb, acc[nt], 0, 0, 0);
      }
    }
  }

  // epilogue: lane holds C[rloc=(lane>>4)*4+j][col=nt*16+ci] for its wave's 16 rows
  const int g = lane >> 4;
  float lg[4];
#pragma unroll
  for (int j = 0; j < 4; ++j) {
    float sacc = 0.f;
#pragma unroll
    for (int nt = 0; nt < 4; ++nt) {
      int c = nt * 16 + ci;
      float z = acc[nt][j] + b1[c];
      z = fmaxf(z, 0.f);
      sacc += z * w2[c];
    }
#pragma unroll
    for (int msk = 1; msk < 16; msk <<= 1) sacc += __shfl_xor(sacc, msk, 64);
    lg[j] = sacc;
  }
  const float b2v = b2[0];
#pragma unroll
  for (int j = 0; j < 4; ++j) {
    int rg = t0 + w * 16 + 4 * g + j;
    if (ci == 0) {
      logit[rg] = lg[j] + b2v;
      pbuf[rg * 2 + 0] = acc[4][j];   // col 64 = w_score[:,0]
    } else if (ci == 1) {
      pbuf[rg * 2 + 1] = acc[4][j];   // col 65 = w_score[:,1]
    }
  }
}

// ---- k2: per-token online prefix softmax over window, 2-dim values
__global__ __launch_bounds__(256) void k2(const float* __restrict__ logit,
                                          const float* __restrict__ pbuf,
                                          const float* __restrict__ bsc,
                                          float* __restrict__ out) {
  int t = blockIdx.x * 256 + threadIdx.x;   // 0..8191
  int s = t & (S_LEN - 1);
  int nmax = min(8, S_LEN - s);
  float bs0 = bsc[0], bs1 = bsc[1];
  float m = logit[t];
  float d = 1.f;
  float n0 = pbuf[2 * t], n1 = pbuf[2 * t + 1];
  float o[16];
  o[0] = n0 + bs0; o[1] = n1 + bs1;
#pragma unroll
  for (int j = 1; j < 8; ++j) {
    if (j < nmax) {
      float L  = logit[t + j];
      float nm = fmaxf(m, L);
      float sc = __expf(m - nm);
      float e  = __expf(L - nm);
      d  = d  * sc + e;
      n0 = n0 * sc + e * pbuf[2 * (t + j)];
      n1 = n1 * sc + e * pbuf[2 * (t + j) + 1];
      m = nm;
    }
    float inv = 1.f / d;
    o[2 * j]     = n0 * inv + bs0;
    o[2 * j + 1] = n1 * inv + bs1;
  }
  float4* op = reinterpret_cast<float4*>(out + (size_t)t * 16);
#pragma unroll
  for (int i = 0; i < 4; ++i) op[i] = *reinterpret_cast<float4*>(&o[4 * i]);
}

extern "C" void kernel_launch(void* const* d_in, const int* in_sizes, int n_in,
                              void* d_out, int out_size, void* d_ws, size_t ws_size,
                              hipStream_t stream) {
  const float* hidden = (const float*)d_in[0];
  const float* tw     = (const float*)d_in[1];
  const float* w1     = (const float*)d_in[2];
  const float* b1     = (const float*)d_in[3];
  const float* w2     = (const float*)d_in[4];
  const float* b2     = (const float*)d_in[5];
  const float* wsc    = (const float*)d_in[6];
  const float* bsc    = (const float*)d_in[7];
  float* out = (float*)d_out;

  char* ws = (char*)d_ws;
  short* wcat  = (short*)ws;                       // 80*768*2   = 122880 B
  float* logit = (float*)(ws + 131072);            // 8192*4     =  32768 B
  float* pbuf  = (float*)(ws + 131072 + 32768);    // 8192*2*4   =  65536 B

  kprep<<<(NCOLS * H_DIM + 255) / 256, 256, 0, stream>>>(tw, w1, wsc, wcat);
  k1<<<BS_TOK / BM, 256, 0, stream>>>(hidden, wcat, b1, w2, b2, logit, pbuf);
  k2<<<BS_TOK / 256, 256, 0, stream>>>(logit, pbuf, bsc, out);
}

// Round 2
// 21.191 us; speedup vs baseline: 2.1469x; 2.1469x over previous
//
#include <hip/hip_runtime.h>

#define S_LEN 512
#define H_DIM 768
#define BS_TOK 8192      // B*S
#define NCOLS 80
#define KSPLIT 4
#define KSEG 192         // H_DIM / KSPLIT
#define KPAD 200         // LDS B row stride (bf16 elements): 400B -> 2-way banks (free)
#define CPAD 68          // partial-C row stride (fp32), 272B = 16B-aligned

typedef __attribute__((ext_vector_type(8))) short short8v;
typedef __attribute__((ext_vector_type(4))) short short4v;
typedef __attribute__((ext_vector_type(4))) float f32x4;

__device__ __forceinline__ short f2bf(float f) {
  union { float f; unsigned u; } x; x.f = f;
  unsigned r = x.u + 0x7fffu + ((x.u >> 16) & 1u);
  return (short)(r >> 16);
}

// ================= fast path (needs ~9MB ws) =================

// k1: barrier-free MFMA GEMM, K split 4 ways, partial C fp32
__global__ __launch_bounds__(256) void k1f(const float* __restrict__ hidden,
                                           const float* __restrict__ tw,
                                           const float* __restrict__ w1,
                                           const float* __restrict__ wsc,
                                           float* __restrict__ part) {
  __shared__ short bs[NCOLS * KPAD];   // 32000 B
  const int tid  = threadIdx.x;
  const int bid  = blockIdx.x;
  const int tile = bid >> 2;           // 0..127
  const int kseg = bid & 3;
  const int k0   = kseg * KSEG;

  // stage B = [diag(tw)*w1 | w_score | 0] for k in [k0,k0+192), layout [col][k]
#pragma unroll
  for (int i = 0; i < 12; ++i) {
    int e = tid + 256 * i;             // 0..3071
    int koff = e >> 4, c4 = e & 15;
    int k = k0 + koff;
    float twk = tw[k];
    float4 w = *reinterpret_cast<const float4*>(w1 + (size_t)k * 64 + c4 * 4);
    bs[(c4 * 4 + 0) * KPAD + koff] = f2bf(w.x * twk);
    bs[(c4 * 4 + 1) * KPAD + koff] = f2bf(w.y * twk);
    bs[(c4 * 4 + 2) * KPAD + koff] = f2bf(w.z * twk);
    bs[(c4 * 4 + 3) * KPAD + koff] = f2bf(w.w * twk);
  }
#pragma unroll
  for (int i = 0; i < 2; ++i) {
    int e = tid + 256 * i;
    if (e < 2 * KSEG) {
      int koff = e >> 1, c = e & 1;
      bs[(64 + c) * KPAD + koff] = f2bf(wsc[(size_t)(k0 + koff) * 2 + c]);
    }
  }
  if (tid < KSEG) {
#pragma unroll
    for (int c = 66; c < 80; ++c) bs[c * KPAD + tid] = 0;
  }
  __syncthreads();   // the ONLY barrier

  const int w    = tid >> 6;
  const int lane = tid & 63;
  const int ci   = lane & 15;
  const int g    = lane >> 4;
  const int kg   = g * 8;
  const int r0   = tile * 64 + w * 16;

  f32x4 acc[5];
#pragma unroll
  for (int nt = 0; nt < 5; ++nt) acc[nt] = (f32x4){0.f, 0.f, 0.f, 0.f};

  const float* aptr = hidden + (size_t)(r0 + ci) * H_DIM + k0 + kg;
#pragma unroll
  for (int ks = 0; ks < KSEG; ks += 32) {
    float4 a0 = *reinterpret_cast<const float4*>(aptr + ks);
    float4 a1 = *reinterpret_cast<const float4*>(aptr + ks + 4);
    short8v av;
    av[0] = f2bf(a0.x); av[1] = f2bf(a0.y); av[2] = f2bf(a0.z); av[3] = f2bf(a0.w);
    av[4] = f2bf(a1.x); av[5] = f2bf(a1.y); av[6] = f2bf(a1.z); av[7] = f2bf(a1.w);
#pragma unroll
    for (int nt = 0; nt < 5; ++nt) {
      short8v bb = *reinterpret_cast<const short8v*>(&bs[(nt * 16 + ci) * KPAD + ks + kg]);
      acc[nt] = __builtin_amdgcn_mfma_f32_16x16x32_bf16(av, bb, acc[nt], 0, 0, 0);
    }
  }

  float* pr = part + ((size_t)kseg * BS_TOK + r0) * CPAD;
#pragma unroll
  for (int j = 0; j < 4; ++j) {
    int r = 4 * g + j;
#pragma unroll
    for (int nt = 0; nt < 4; ++nt)
      pr[r * CPAD + nt * 16 + ci] = acc[nt][j];
    if (ci < 2) pr[r * CPAD + 64 + ci] = acc[4][j];
  }
}

// k2: reduce K-partials + relu-MLP epilogue -> logit, p
__global__ __launch_bounds__(256) void k2f(const float* __restrict__ part,
                                           const float* __restrict__ b1,
                                           const float* __restrict__ w2,
                                           const float* __restrict__ b2,
                                           float* __restrict__ logit,
                                           float* __restrict__ pbuf) {
  const int tid  = threadIdx.x;
  const int w    = tid >> 6;
  const int lane = tid & 63;
  const int ci   = lane & 15;
  const int tt   = blockIdx.x * 16 + w * 4 + (lane >> 4);

  f32x4 s = (f32x4){0.f, 0.f, 0.f, 0.f};
#pragma unroll
  for (int seg = 0; seg < KSPLIT; ++seg) {
    const float4 v = *reinterpret_cast<const float4*>(
        part + ((size_t)seg * BS_TOK + tt) * CPAD + 4 * ci);
    s[0] += v.x; s[1] += v.y; s[2] += v.z; s[3] += v.w;
  }
  const float4 bb = *reinterpret_cast<const float4*>(b1 + 4 * ci);
  const float4 ww = *reinterpret_cast<const float4*>(w2 + 4 * ci);
  float r = fmaxf(s[0] + bb.x, 0.f) * ww.x + fmaxf(s[1] + bb.y, 0.f) * ww.y +
            fmaxf(s[2] + bb.z, 0.f) * ww.z + fmaxf(s[3] + bb.w, 0.f) * ww.w;
#pragma unroll
  for (int msk = 1; msk < 16; msk <<= 1) r += __shfl_xor(r, msk, 64);

  if (ci < 2) {
    float pv = 0.f;
#pragma unroll
    for (int seg = 0; seg < KSPLIT; ++seg)
      pv += part[((size_t)seg * BS_TOK + tt) * CPAD + 64 + ci];
    if (ci == 0) logit[tt] = r + b2[0];
    pbuf[2 * tt + ci] = pv;
  }
}

// k3: per-token online prefix softmax over window, 2-dim values
__global__ __launch_bounds__(256) void k3(const float* __restrict__ logit,
                                          const float* __restrict__ pbuf,
                                          const float* __restrict__ bsc,
                                          float* __restrict__ out) {
  int t = blockIdx.x * 256 + threadIdx.x;
  int s = t & (S_LEN - 1);
  int nmax = min(8, S_LEN - s);
  float bs0 = bsc[0], bs1 = bsc[1];
  float m = logit[t];
  float d = 1.f;
  float n0 = pbuf[2 * t], n1 = pbuf[2 * t + 1];
  float o[16];
  o[0] = n0 + bs0; o[1] = n1 + bs1;
#pragma unroll
  for (int j = 1; j < 8; ++j) {
    if (j < nmax) {
      float L  = logit[t + j];
      float nm = fmaxf(m, L);
      float sc = __expf(m - nm);
      float e  = __expf(L - nm);
      d  = d  * sc + e;
      n0 = n0 * sc + e * pbuf[2 * (t + j)];
      n1 = n1 * sc + e * pbuf[2 * (t + j) + 1];
      m = nm;
    }
    float inv = 1.f / d;
    o[2 * j]     = n0 * inv + bs0;
    o[2 * j + 1] = n1 * inv + bs1;
  }
  float4* op = reinterpret_cast<float4*>(out + (size_t)t * 16);
#pragma unroll
  for (int i = 0; i < 4; ++i) op[i] = *reinterpret_cast<float4*>(&o[4 * i]);
}

// ================= fallback path (small ws; round-1 kernels) =================

__global__ __launch_bounds__(256) void kprep(const float* __restrict__ tw,
                                             const float* __restrict__ w1,
                                             const float* __restrict__ wsc,
                                             short* __restrict__ wcat) {
  int i = blockIdx.x * 256 + threadIdx.x;
  if (i >= NCOLS * H_DIM) return;
  int c = i / H_DIM, k = i - c * H_DIM;
  float v = 0.f;
  if (c < 64)       v = tw[k] * w1[k * 64 + c];
  else if (c == 64) v = wsc[k * 2 + 0];
  else if (c == 65) v = wsc[k * 2 + 1];
  wcat[i] = f2bf(v);
}

__global__ __launch_bounds__(256) void k1s(const float* __restrict__ hidden,
                                           const short* __restrict__ wcat,
                                           const float* __restrict__ b1,
                                           const float* __restrict__ w2,
                                           const float* __restrict__ b2,
                                           float* __restrict__ logit,
                                           float* __restrict__ pbuf) {
  __shared__ short as[64 * 72];
  __shared__ short bss[NCOLS * 72];
  const int tid  = threadIdx.x;
  const int t0   = blockIdx.x * 64;
  const int w    = tid >> 6;
  const int lane = tid & 63;
  const int ci   = lane & 15;
  const int kg   = (lane >> 4) * 8;
  const int arow = w * 16 + ci;

  f32x4 acc[5];
#pragma unroll
  for (int nt = 0; nt < 5; ++nt) acc[nt] = (f32x4){0.f, 0.f, 0.f, 0.f};

  for (int cc = 0; cc < H_DIM / 64; ++cc) {
    const int k0 = cc * 64;
    __syncthreads();
#pragma unroll
    for (int i = 0; i < 4; ++i) {
      int f = tid + 256 * i;
      int r = f >> 4, c4 = f & 15;
      const float4 v = *reinterpret_cast<const float4*>(
          hidden + (size_t)(t0 + r) * H_DIM + k0 + c4 * 4);
      short4v bv;
      bv[0] = f2bf(v.x); bv[1] = f2bf(v.y); bv[2] = f2bf(v.z); bv[3] = f2bf(v.w);
      *reinterpret_cast<short4v*>(&as[r * 72 + c4 * 4]) = bv;
    }
    for (int i = tid; i < NCOLS * 8; i += 256) {
      int r = i >> 3, c8 = i & 7;
      short8v v = *reinterpret_cast<const short8v*>(wcat + r * H_DIM + k0 + c8 * 8);
      *reinterpret_cast<short8v*>(&bss[r * 72 + c8 * 8]) = v;
    }
    __syncthreads();
#pragma unroll
    for (int ks = 0; ks < 64; ks += 32) {
      short8v a = *reinterpret_cast<const short8v*>(&as[arow * 72 + ks + kg]);
#pragma unroll
      for (int nt = 0; nt < 5; ++nt) {
        short8v bb = *reinterpret_cast<const short8v*>(&bss[(nt * 16 + ci) * 72 + ks + kg]);
        acc[nt] = __builtin_amdgcn_mfma_f32_16x16x32_bf16(a, bb, acc[nt], 0, 0, 0);
      }
    }
  }

  const int g = lane >> 4;
  float lg[4];
#pragma unroll
  for (int j = 0; j < 4; ++j) {
    float sacc = 0.f;
#pragma unroll
    for (int nt = 0; nt < 4; ++nt) {
      int c = nt * 16 + ci;
      float z = acc[nt][j] + b1[c];
      z = fmaxf(z, 0.f);
      sacc += z * w2[c];
    }
#pragma unroll
    for (int msk = 1; msk < 16; msk <<= 1) sacc += __shfl_xor(sacc, msk, 64);
    lg[j] = sacc;
  }
  const float b2v = b2[0];
#pragma unroll
  for (int j = 0; j < 4; ++j) {
    int rg = t0 + w * 16 + 4 * g + j;
    if (ci == 0) {
      logit[rg] = lg[j] + b2v;
      pbuf[rg * 2 + 0] = acc[4][j];
    } else if (ci == 1) {
      pbuf[rg * 2 + 1] = acc[4][j];
    }
  }
}

// ================= launch =================

extern "C" void kernel_launch(void* const* d_in, const int* in_sizes, int n_in,
                              void* d_out, int out_size, void* d_ws, size_t ws_size,
                              hipStream_t stream) {
  const float* hidden = (const float*)d_in[0];
  const float* tw     = (const float*)d_in[1];
  const float* w1     = (const float*)d_in[2];
  const float* b1     = (const float*)d_in[3];
  const float* w2     = (const float*)d_in[4];
  const float* b2     = (const float*)d_in[5];
  const float* wsc    = (const float*)d_in[6];
  const float* bsc    = (const float*)d_in[7];
  float* out = (float*)d_out;
  char* ws = (char*)d_ws;

  const size_t part_bytes = (size_t)KSPLIT * BS_TOK * CPAD * 4;  // 8,912,896
  const size_t need_fast  = part_bytes + 32768 + 65536;

  if (ws_size >= need_fast) {
    float* part  = (float*)ws;
    float* logit = (float*)(ws + part_bytes);
    float* pbuf  = (float*)(ws + part_bytes + 32768);
    k1f<<<(BS_TOK / 64) * KSPLIT, 256, 0, stream>>>(hidden, tw, w1, wsc, part);
    k2f<<<BS_TOK / 16, 256, 0, stream>>>(part, b1, w2, b2, logit, pbuf);
    k3 <<<BS_TOK / 256, 256, 0, stream>>>(logit, pbuf, bsc, out);
  } else {
    short* wcat  = (short*)ws;
    float* logit = (float*)(ws + 131072);
    float* pbuf  = (float*)(ws + 131072 + 32768);
    kprep<<<(NCOLS * H_DIM + 255) / 256, 256, 0, stream>>>(tw, w1, wsc, wcat);
    k1s<<<BS_TOK / 64, 256, 0, stream>>>(hidden, wcat, b1, w2, b2, logit, pbuf);
    k3<<<BS_TOK / 256, 256, 0, stream>>>(logit, pbuf, bsc, out);
  }
}